// Round 6
// baseline (464.179 us; speedup 1.0000x reference)
//
#include <hip/hip_runtime.h>
#include <math.h>

// Problem constants: B=2, S=2048, D=2048, K=8, F=D/4=512, R=8
#define B_ 2
#define S_ 2048
#define T_ (B_*S_)
#define D_ 2048
#define K_ 8
#define F_ 512
#define R_ 8
#define WSEG 16   // s-segment per window block

typedef unsigned short ushort_t;
typedef __attribute__((__ext_vector_type__(8))) __bf16 bf16x8;
typedef __attribute__((__ext_vector_type__(4))) float f32x4;

__device__ __forceinline__ float bf2f(ushort_t u) {
    return __uint_as_float(((unsigned int)u) << 16);
}
__device__ __forceinline__ ushort_t f2bf(float f) {
    unsigned int u = __float_as_uint(f);
    unsigned int r = u + 0x7FFFu + ((u >> 16) & 1u);
    return (ushort_t)(r >> 16);
}
__device__ __forceinline__ float loadF(const void* p, size_t idx, int f32m) {
    if (f32m) return ((const float*)p)[idx];
    return bf2f(((const ushort_t*)p)[idx]);
}

// 16B global->LDS staging; async direct-to-LDS when available (m97: 1.69x).
#if defined(__has_builtin)
#if __has_builtin(__builtin_amdgcn_global_load_lds)
#define ASYNC_LDS 1
#endif
#endif
__device__ __forceinline__ void ld16_lds(void* l, const void* g) {
#ifdef ASYNC_LDS
    __builtin_amdgcn_global_load_lds((const __attribute__((address_space(1))) unsigned int*)g,
                                     (__attribute__((address_space(3))) unsigned int*)l,
                                     16, 0, 0);
#else
    *(uint4*)l = *(const uint4*)g;
#endif
}

// ---------------- layout/dtype detection ----------------
__global__ void detect_kernel(const unsigned char* __restrict__ hraw,
                              const unsigned char* __restrict__ mraw,
                              int* __restrict__ modePtr) {
    __shared__ int has_non01, has_nz123, has_3F1, outlier;
    if (threadIdx.x == 0) { has_non01 = 0; has_nz123 = 0; has_3F1 = 0; outlier = 0; }
    __syncthreads();
    int a = 0, b = 0, c = 0, o = 0;
    for (int i = threadIdx.x; i < 4096; i += 256) {
        unsigned char v = mraw[i];
        if (v > 1) a = 1;
        if ((i & 3) != 0 && v != 0) b = 1;
        if ((i & 3) == 1 && v >= 2) c = 1;
        if ((i & 3) == 1) {
            unsigned char hb = hraw[i] & 0x7F;
            if (hb < 0x30 || hb > 0x47) o++;
        }
    }
    if (a) atomicOr(&has_non01, 1);
    if (b) atomicOr(&has_nz123, 1);
    if (c) atomicOr(&has_3F1, 1);
    if (o) atomicAdd(&outlier, o);
    __syncthreads();
    if (threadIdx.x == 0) {
        int mode;
        if (!has_non01) mode = has_nz123 ? 0 : 1;
        else            mode = has_3F1 ? 2 : 3;
        modePtr[0] = mode;
        modePtr[1] = (outlier > 256) ? 1 : 0;
    }
}

// ---------------- mask prep: maskI, unmasked-index compaction, invcnt, valid ----------------
__global__ __launch_bounds__(256) void mask_prep_kernel(const void* __restrict__ raw,
                                                        const int* __restrict__ modePtr,
                                                        int* __restrict__ maskI,
                                                        int* __restrict__ idx,
                                                        int* __restrict__ TcPtr,
                                                        float* __restrict__ invcnt,
                                                        int* __restrict__ valid) {
    __shared__ int sm[T_];        // 16 KB
    __shared__ int cnts[257];
    const int tid = threadIdx.x;
    const int mode = modePtr[0];
    for (int t = tid; t < T_; t += 256) {
        int m;
        if (mode == 0)      m = ((const unsigned char*)raw)[t] != 0;
        else if (mode == 1) m = ((const int*)raw)[t] != 0;
        else if (mode == 2) m = ((const ushort_t*)raw)[t] != 0;
        else                m = ((const unsigned int*)raw)[t] != 0;
        sm[t] = m;
        maskI[t] = m;
    }
    __syncthreads();
    const int base = tid * 16;
    int cnt = 0;
#pragma unroll
    for (int u = 0; u < 16; ++u) cnt += (sm[base + u] == 0);
    cnts[tid] = cnt;
    __syncthreads();
    if (tid == 0) {
        int run = 0;
        for (int i = 0; i < 256; ++i) { int c = cnts[i]; cnts[i] = run; run += c; }
        cnts[256] = run;
    }
    __syncthreads();
    int run = cnts[tid];
#pragma unroll
    for (int u = 0; u < 16; ++u) {
        int t = base + u;
        if (!sm[t]) idx[run++] = t;
    }
    const int Tc = cnts[256];
    for (int i = Tc + tid; i < T_; i += 256) idx[i] = T_;   // sentinel
    if (tid == 0) TcPtr[0] = Tc;
    for (int t = tid; t < T_; t += 256) {
        int b = t >> 11, s = t & (S_ - 1);
        int lo = s - R_; if (lo < 0) lo = 0;
        int hi = s + R_; if (hi > S_ - 1) hi = S_ - 1;
        int c = 0;
        for (int sp = lo; sp <= hi; ++sp) c += (sm[b * S_ + sp] == 0);
        c -= (sm[t] == 0);
        invcnt[t] = 1.0f / fmaxf((float)c, 1.0f);
        valid[t] = (sm[t] && c > 0) ? 1 : 0;
    }
}

// ---------------- compact h rows -> bf16 ----------------
__global__ __launch_bounds__(256) void conv_hc_kernel(const void* __restrict__ hraw,
                                                      const int* __restrict__ modePtr,
                                                      const int* __restrict__ idx,
                                                      const int* __restrict__ TcPtr,
                                                      ushort_t* __restrict__ hbfc) {
    int gid = blockIdx.x * 256 + threadIdx.x;
    int i = gid >> 8;                 // one block per compacted row
    if (i >= *TcPtr) return;
    int col = (gid & 255) * 8;
    size_t src = (size_t)idx[i] * D_ + col;
    size_t dst = (size_t)i * D_ + col;
    if (modePtr[1]) {
        const float* p = (const float*)hraw + src;
        float4 a = *(const float4*)p;
        float4 b = *(const float4*)(p + 4);
        uint4 o;
        o.x = (unsigned)f2bf(a.x) | ((unsigned)f2bf(a.y) << 16);
        o.y = (unsigned)f2bf(a.z) | ((unsigned)f2bf(a.w) << 16);
        o.z = (unsigned)f2bf(b.x) | ((unsigned)f2bf(b.y) << 16);
        o.w = (unsigned)f2bf(b.z) | ((unsigned)f2bf(b.w) << 16);
        *(uint4*)&hbfc[dst] = o;
    } else {
        *(uint4*)&hbfc[dst] = *(const uint4*)((const ushort_t*)hraw + src);
    }
}

// ---------------- router: softmax(h @ W_route + b_route), masked tokens only ----------------
__global__ __launch_bounds__(256) void router_kernel(const void* __restrict__ hraw,
                                                     const void* __restrict__ Wr,
                                                     const void* __restrict__ br,
                                                     const int* __restrict__ modePtr,
                                                     const int* __restrict__ maskI,
                                                     float* __restrict__ wout) {
    int t = blockIdx.x;
    if (!maskI[t]) return;
    int f32m = modePtr[1];
    float p[8];
#pragma unroll
    for (int k = 0; k < 8; ++k) p[k] = 0.f;
    if (f32m) {
        for (int d = threadIdx.x; d < D_; d += 256) {
            float hv = ((const float*)hraw)[(size_t)t * D_ + d];
            const float* wrow = (const float*)Wr + (size_t)d * 8;
            float4 q0 = *(const float4*)wrow;
            float4 q1 = *(const float4*)(wrow + 4);
            p[0] += hv * q0.x; p[1] += hv * q0.y; p[2] += hv * q0.z; p[3] += hv * q0.w;
            p[4] += hv * q1.x; p[5] += hv * q1.y; p[6] += hv * q1.z; p[7] += hv * q1.w;
        }
    } else {
        const ushort_t* Wrb = (const ushort_t*)Wr;
        for (int d = threadIdx.x; d < D_; d += 256) {
            float hv = bf2f(((const ushort_t*)hraw)[(size_t)t * D_ + d]);
            uint4 q = *(const uint4*)&Wrb[(size_t)d * 8];
            p[0] += hv * __uint_as_float(q.x << 16);
            p[1] += hv * __uint_as_float(q.x & 0xFFFF0000u);
            p[2] += hv * __uint_as_float(q.y << 16);
            p[3] += hv * __uint_as_float(q.y & 0xFFFF0000u);
            p[4] += hv * __uint_as_float(q.z << 16);
            p[5] += hv * __uint_as_float(q.z & 0xFFFF0000u);
            p[6] += hv * __uint_as_float(q.w << 16);
            p[7] += hv * __uint_as_float(q.w & 0xFFFF0000u);
        }
    }
#pragma unroll
    for (int off = 32; off; off >>= 1)
#pragma unroll
        for (int k = 0; k < 8; ++k) p[k] += __shfl_down(p[k], off);
    __shared__ float sm[4][8];
    int w = threadIdx.x >> 6, lane = threadIdx.x & 63;
    if (lane == 0)
#pragma unroll
        for (int k = 0; k < 8; ++k) sm[w][k] = p[k];
    __syncthreads();
    if (threadIdx.x == 0) {
        float lg[8];
        float mx = -1e30f;
#pragma unroll
        for (int k = 0; k < 8; ++k) {
            lg[k] = sm[0][k] + sm[1][k] + sm[2][k] + sm[3][k] + loadF(br, k, f32m);
            mx = fmaxf(mx, lg[k]);
        }
        float ssum = 0.f;
#pragma unroll
        for (int k = 0; k < 8; ++k) { lg[k] = __expf(lg[k] - mx); ssum += lg[k]; }
        float inv = 1.0f / ssum;
#pragma unroll
        for (int k = 0; k < 8; ++k) wout[t * 8 + k] = lg[k] * inv;
    }
}

// ---------------- dtype-aware 32x32 transpose of expert slice (z=expert) ----------------
__global__ __launch_bounds__(256) void transpose_kernel(const void* __restrict__ in,
                                                        ushort_t* __restrict__ op,
                                                        int rows, int cols,
                                                        const int* __restrict__ modePtr) {
    __shared__ ushort_t tile[32][33];
    int f32m = modePtr[1];
    int kexp = blockIdx.z;
    size_t base = (size_t)kexp * rows * cols;
    ushort_t* ob = op + (size_t)kexp * rows * cols;
    int r0 = blockIdx.x * 32, c0 = blockIdx.y * 32;
    int tx = threadIdx.x & 31, ty = threadIdx.x >> 5;
#pragma unroll
    for (int i = 0; i < 4; ++i) {
        int r = ty + i * 8;
        tile[r][tx] = f2bf(loadF(in, base + (size_t)(r0 + r) * cols + c0 + tx, f32m));
    }
    __syncthreads();
#pragma unroll
    for (int i = 0; i < 4; ++i) {
        int c = ty + i * 8;
        ob[(size_t)(c0 + c) * rows + r0 + tx] = tile[tx][c];
    }
}

// ---------------- GEMM1 (experts merged into N, double-buffered) ----------------
// C[i][n] = gelu(hbfc @ W1t^T + b1), M=Tc, N=K_*F_=4096, K=D_.
// W1t [K][F][D] contiguous == B^T [4096][2048]. b1 flat index == n.
// Output scattered to hidc[k=n>>9][i][f=n&511].
__global__ __launch_bounds__(256) void gemm1_kernel(const ushort_t* __restrict__ hbfc,
                                                    const ushort_t* __restrict__ W1t,
                                                    const void* __restrict__ b1,
                                                    const int* __restrict__ modePtr,
                                                    const int* __restrict__ TcPtr,
                                                    ushort_t* __restrict__ hidc) {
    const int bm = blockIdx.x;
    if (bm * 128 >= *TcPtr) return;   // block-uniform early exit
    __shared__ ushort_t Al[2][128 * 32];
    __shared__ ushort_t Bl[2][128 * 32];
    const int f32m = modePtr[1];
    const int bn = blockIdx.y;
    const int tid = threadIdx.x;
    const int lane = tid & 63, w = tid >> 6;
    const int lm = lane & 15, quad = lane >> 4;
    const int wm = (w >> 1) * 64, wn = (w & 1) * 64;
    const ushort_t* Ab = hbfc + (size_t)(bm * 128) * D_;
    const ushort_t* Bb = W1t + (size_t)(bn * 128) * D_;
    f32x4 acc[4][4];
    const f32x4 zz = {0.f, 0.f, 0.f, 0.f};
#pragma unroll
    for (int i = 0; i < 4; ++i)
#pragma unroll
        for (int j = 0; j < 4; ++j) acc[i][j] = zz;
    const int r0 = tid >> 2, c0 = (tid & 3) * 8;
    // prologue: stage kt=0 into buf 0
    ld16_lds(&Al[0][r0 * 32 + c0],        &Ab[(size_t)r0 * D_ + c0]);
    ld16_lds(&Al[0][(r0 + 64) * 32 + c0], &Ab[(size_t)(r0 + 64) * D_ + c0]);
    ld16_lds(&Bl[0][r0 * 32 + c0],        &Bb[(size_t)r0 * D_ + c0]);
    ld16_lds(&Bl[0][(r0 + 64) * 32 + c0], &Bb[(size_t)(r0 + 64) * D_ + c0]);
    __syncthreads();
    int p = 0;
    for (int kt = 0; kt < D_ / 32; ++kt) {
        const int q = p ^ 1;
        if (kt + 1 < D_ / 32) {
            const int kb = (kt + 1) * 32;   // prefetch next tile BEFORE compute
            ld16_lds(&Al[q][r0 * 32 + c0],        &Ab[(size_t)r0 * D_ + kb + c0]);
            ld16_lds(&Al[q][(r0 + 64) * 32 + c0], &Ab[(size_t)(r0 + 64) * D_ + kb + c0]);
            ld16_lds(&Bl[q][r0 * 32 + c0],        &Bb[(size_t)r0 * D_ + kb + c0]);
            ld16_lds(&Bl[q][(r0 + 64) * 32 + c0], &Bb[(size_t)(r0 + 64) * D_ + kb + c0]);
        }
        bf16x8 af[4], bfr[4];
#pragma unroll
        for (int i = 0; i < 4; ++i) af[i] = *(const bf16x8*)&Al[p][(wm + i * 16 + lm) * 32 + quad * 8];
#pragma unroll
        for (int j = 0; j < 4; ++j) bfr[j] = *(const bf16x8*)&Bl[p][(wn + j * 16 + lm) * 32 + quad * 8];
#pragma unroll
        for (int i = 0; i < 4; ++i)
#pragma unroll
            for (int j = 0; j < 4; ++j)
                acc[i][j] = __builtin_amdgcn_mfma_f32_16x16x32_bf16(af[i], bfr[j], acc[i][j], 0, 0, 0);
        __syncthreads();   // vmcnt(0) drain lands AFTER compute covered load latency
        p = q;
    }
#pragma unroll
    for (int j = 0; j < 4; ++j) {
        int n = bn * 128 + wn + j * 16 + lm;
        int kexp = n >> 9, fg = n & 511;
        float bias = loadF(b1, (size_t)n, f32m);
#pragma unroll
        for (int i = 0; i < 4; ++i) {
            int mb = bm * 128 + wm + i * 16 + quad * 4;
#pragma unroll
            for (int v = 0; v < 4; ++v) {
                float x = acc[i][j][v] + bias;
                float g = 0.5f * x * (1.0f + erff(x * 0.70710678118654752f));
                hidc[(size_t)kexp * T_ * F_ + (size_t)(mb + v) * F_ + fg] = f2bf(g);
            }
        }
    }
}

// ---------------- GEMM2 (z=expert, compacted rows, scatter, double-buffered) ----------------
__global__ __launch_bounds__(256) void gemm2_kernel(const ushort_t* __restrict__ hidc,
                                                    const ushort_t* __restrict__ W2t,
                                                    const void* __restrict__ b2,
                                                    const int* __restrict__ modePtr,
                                                    const int* __restrict__ TcPtr,
                                                    const int* __restrict__ idx,
                                                    ushort_t* __restrict__ eo) {
    const int bm = blockIdx.x;
    if (bm * 128 >= *TcPtr) return;
    __shared__ ushort_t Al[2][128 * 32];
    __shared__ ushort_t Bl[2][128 * 32];
    __shared__ int sidx[128];
    const int f32m = modePtr[1];
    const int kexp = blockIdx.z;
    const int bn = blockIdx.y;
    const int tid = threadIdx.x;
    if (tid < 128) sidx[tid] = idx[bm * 128 + tid];
    const int lane = tid & 63, w = tid >> 6;
    const int lm = lane & 15, quad = lane >> 4;
    const int wm = (w >> 1) * 64, wn = (w & 1) * 64;
    const ushort_t* Ab = hidc + (size_t)kexp * T_ * F_ + (size_t)(bm * 128) * F_;
    const ushort_t* Bb = W2t + (size_t)kexp * D_ * F_ + (size_t)(bn * 128) * F_;
    f32x4 acc[4][4];
    const f32x4 zz = {0.f, 0.f, 0.f, 0.f};
#pragma unroll
    for (int i = 0; i < 4; ++i)
#pragma unroll
        for (int j = 0; j < 4; ++j) acc[i][j] = zz;
    const int r0 = tid >> 2, c0 = (tid & 3) * 8;
    ld16_lds(&Al[0][r0 * 32 + c0],        &Ab[(size_t)r0 * F_ + c0]);
    ld16_lds(&Al[0][(r0 + 64) * 32 + c0], &Ab[(size_t)(r0 + 64) * F_ + c0]);
    ld16_lds(&Bl[0][r0 * 32 + c0],        &Bb[(size_t)r0 * F_ + c0]);
    ld16_lds(&Bl[0][(r0 + 64) * 32 + c0], &Bb[(size_t)(r0 + 64) * F_ + c0]);
    __syncthreads();
    int p = 0;
    for (int kt = 0; kt < F_ / 32; ++kt) {
        const int q = p ^ 1;
        if (kt + 1 < F_ / 32) {
            const int kb = (kt + 1) * 32;
            ld16_lds(&Al[q][r0 * 32 + c0],        &Ab[(size_t)r0 * F_ + kb + c0]);
            ld16_lds(&Al[q][(r0 + 64) * 32 + c0], &Ab[(size_t)(r0 + 64) * F_ + kb + c0]);
            ld16_lds(&Bl[q][r0 * 32 + c0],        &Bb[(size_t)r0 * F_ + kb + c0]);
            ld16_lds(&Bl[q][(r0 + 64) * 32 + c0], &Bb[(size_t)(r0 + 64) * F_ + kb + c0]);
        }
        bf16x8 af[4], bfr[4];
#pragma unroll
        for (int i = 0; i < 4; ++i) af[i] = *(const bf16x8*)&Al[p][(wm + i * 16 + lm) * 32 + quad * 8];
#pragma unroll
        for (int j = 0; j < 4; ++j) bfr[j] = *(const bf16x8*)&Bl[p][(wn + j * 16 + lm) * 32 + quad * 8];
#pragma unroll
        for (int i = 0; i < 4; ++i)
#pragma unroll
            for (int j = 0; j < 4; ++j)
                acc[i][j] = __builtin_amdgcn_mfma_f32_16x16x32_bf16(af[i], bfr[j], acc[i][j], 0, 0, 0);
        __syncthreads();
        p = q;
    }
#pragma unroll
    for (int j = 0; j < 4; ++j) {
        int dg = bn * 128 + wn + j * 16 + lm;
        float bias = loadF(b2, (size_t)kexp * D_ + dg, f32m);
#pragma unroll
        for (int i = 0; i < 4; ++i) {
            int lr = wm + i * 16 + quad * 4;
#pragma unroll
            for (int v = 0; v < 4; ++v) {
                int tok = sidx[lr + v];   // sentinel T_ for padded rows
                float x = acc[i][j][v] + bias;
                eo[((size_t)tok * K_ + kexp) * D_ + dg] = f2bf(x);
            }
        }
    }
}

// ---------------- sliding window over all experts + routing mix (skips masked rows) ----------------
__device__ __forceinline__ void acc8add(float* run, const ushort_t* p) {
    const uint4 q = *(const uint4*)p;
    run[0] += __uint_as_float(q.x << 16);
    run[1] += __uint_as_float(q.x & 0xFFFF0000u);
    run[2] += __uint_as_float(q.y << 16);
    run[3] += __uint_as_float(q.y & 0xFFFF0000u);
    run[4] += __uint_as_float(q.z << 16);
    run[5] += __uint_as_float(q.z & 0xFFFF0000u);
    run[6] += __uint_as_float(q.w << 16);
    run[7] += __uint_as_float(q.w & 0xFFFF0000u);
}
__device__ __forceinline__ void acc8sub(float* run, const ushort_t* p) {
    const uint4 q = *(const uint4*)p;
    run[0] -= __uint_as_float(q.x << 16);
    run[1] -= __uint_as_float(q.x & 0xFFFF0000u);
    run[2] -= __uint_as_float(q.y << 16);
    run[3] -= __uint_as_float(q.y & 0xFFFF0000u);
    run[4] -= __uint_as_float(q.z << 16);
    run[5] -= __uint_as_float(q.z & 0xFFFF0000u);
    run[6] -= __uint_as_float(q.w << 16);
    run[7] -= __uint_as_float(q.w & 0xFFFF0000u);
}

__global__ __launch_bounds__(256) void window_all_kernel(const ushort_t* __restrict__ eo,
                                                         const float* __restrict__ wR,
                                                         const int* __restrict__ maskI,
                                                         const float* __restrict__ invcnt,
                                                         float* __restrict__ mixed) {
    const int b = blockIdx.y;
    const int s0 = blockIdx.x * WSEG;
    const int d0 = threadIdx.x * 8;
    float run[K_][8];
#pragma unroll
    for (int k = 0; k < K_; ++k)
#pragma unroll
        for (int j = 0; j < 8; ++j) run[k][j] = 0.f;
    int lo = s0 - R_; if (lo < 0) lo = 0;
    for (int sp = lo; sp < s0 + R_; ++sp) {
        if (maskI[b * S_ + sp]) continue;
        const ushort_t* row = &eo[(size_t)(b * S_ + sp) * K_ * D_ + d0];
#pragma unroll
        for (int k = 0; k < K_; ++k) acc8add(run[k], row + (size_t)k * D_);
    }
    for (int s = s0; s < s0 + WSEG; ++s) {
        const int t = b * S_ + s;
        if (s + R_ < S_ && !maskI[t + R_]) {
            const ushort_t* row = &eo[(size_t)(t + R_) * K_ * D_ + d0];
#pragma unroll
            for (int k = 0; k < K_; ++k) acc8add(run[k], row + (size_t)k * D_);
        }
        if (maskI[t]) {
            float ic = invcnt[t];
            float o[8];
#pragma unroll
            for (int j = 0; j < 8; ++j) o[j] = 0.f;
#pragma unroll
            for (int k = 0; k < K_; ++k) {
                float wk = wR[t * K_ + k] * ic;
#pragma unroll
                for (int j = 0; j < 8; ++j) o[j] += wk * run[k][j];
            }
            float4 o0 = {o[0], o[1], o[2], o[3]};
            float4 o1 = {o[4], o[5], o[6], o[7]};
            *(float4*)&mixed[(size_t)t * D_ + d0]     = o0;
            *(float4*)&mixed[(size_t)t * D_ + d0 + 4] = o1;
        }
        if (s - R_ >= 0 && !maskI[t - R_]) {
            const ushort_t* row = &eo[(size_t)(t - R_) * K_ * D_ + d0];
#pragma unroll
            for (int k = 0; k < K_; ++k) acc8sub(run[k], row + (size_t)k * D_);
        }
    }
}

// ---------------- LayerNorm + validity mask; dtype-aware output ----------------
__global__ __launch_bounds__(256) void ln_kernel(const float* __restrict__ mixed,
                                                 const int* __restrict__ valid,
                                                 const int* __restrict__ modePtr,
                                                 void* __restrict__ out) {
    const int t = blockIdx.x;
    const int tid = threadIdx.x;
    const int f32m = modePtr[1];
    if (!valid[t]) {
        if (f32m) {
            float4 z = {0.f, 0.f, 0.f, 0.f};
            float* op = (float*)out + (size_t)t * D_ + tid * 8;
            *(float4*)op = z; *(float4*)(op + 4) = z;
        } else {
            uint4 z = {0u, 0u, 0u, 0u};
            *(uint4*)((ushort_t*)out + (size_t)t * D_ + tid * 8) = z;
        }
        return;
    }
    float4 a = *(const float4*)&mixed[(size_t)t * D_ + tid * 8];
    float4 c = *(const float4*)&mixed[(size_t)t * D_ + tid * 8 + 4];
    float xs[8] = {a.x, a.y, a.z, a.w, c.x, c.y, c.z, c.w};
    float s1 = 0.f, s2 = 0.f;
#pragma unroll
    for (int j = 0; j < 8; ++j) { s1 += xs[j]; s2 += xs[j] * xs[j]; }
#pragma unroll
    for (int off = 32; off; off >>= 1) { s1 += __shfl_down(s1, off); s2 += __shfl_down(s2, off); }
    __shared__ float sm[8];
    int w = tid >> 6;
    if ((tid & 63) == 0) { sm[w * 2] = s1; sm[w * 2 + 1] = s2; }
    __syncthreads();
    float ts1 = sm[0] + sm[2] + sm[4] + sm[6];
    float ts2 = sm[1] + sm[3] + sm[5] + sm[7];
    float mu = ts1 * (1.0f / D_);
    float var = fmaxf(ts2 * (1.0f / D_) - mu * mu, 0.0f);
    float inv = rsqrtf(var + 1e-5f);
    if (f32m) {
        float* op = (float*)out + (size_t)t * D_ + tid * 8;
        float4 o0 = {(xs[0] - mu) * inv, (xs[1] - mu) * inv, (xs[2] - mu) * inv, (xs[3] - mu) * inv};
        float4 o1 = {(xs[4] - mu) * inv, (xs[5] - mu) * inv, (xs[6] - mu) * inv, (xs[7] - mu) * inv};
        *(float4*)op = o0; *(float4*)(op + 4) = o1;
    } else {
        ushort_t ob[8];
#pragma unroll
        for (int j = 0; j < 8; ++j) ob[j] = f2bf((xs[j] - mu) * inv);
        uint4 o;
        o.x = (unsigned)ob[0] | ((unsigned)ob[1] << 16);
        o.y = (unsigned)ob[2] | ((unsigned)ob[3] << 16);
        o.z = (unsigned)ob[4] | ((unsigned)ob[5] << 16);
        o.w = (unsigned)ob[6] | ((unsigned)ob[7] << 16);
        *(uint4*)((ushort_t*)out + (size_t)t * D_ + tid * 8) = o;
    }
}

extern "C" void kernel_launch(void* const* d_in, const int* in_sizes, int n_in,
                              void* d_out, int out_size, void* d_ws, size_t ws_size,
                              hipStream_t stream) {
    const void* h    = d_in[0];
    const void* mraw = d_in[1];
    const void* Wr   = d_in[2];
    const void* br   = d_in[3];
    const void* W1   = d_in[4];
    const void* b1   = d_in[5];
    const void* W2   = d_in[6];
    const void* b2   = d_in[7];
    (void)in_sizes; (void)n_in; (void)out_size; (void)ws_size;

    char* ws = (char*)d_ws;
    size_t off = 0;
    auto alloc = [&](size_t bytes) -> void* {
        void* p = ws + off;
        off += (bytes + 255) & ~(size_t)255;
        return p;
    };
    ushort_t* hbfc  = (ushort_t*)alloc((size_t)T_ * D_ * 2);              // 16.8 MB
    ushort_t* W1t   = (ushort_t*)alloc((size_t)K_ * F_ * D_ * 2);         // 16.8 MB [K][F][D] == B^T[4096][2048]
    ushort_t* W2t   = (ushort_t*)alloc((size_t)K_ * D_ * F_ * 2);         // 16.8 MB [K][D][F]
    ushort_t* hidc  = (ushort_t*)alloc((size_t)K_ * T_ * F_ * 2);         // 33.6 MB [K][Tc][F]
    ushort_t* eo    = (ushort_t*)alloc(((size_t)T_ + 1) * K_ * D_ * 2);   // 134 MB + sentinel row
    float*    wRbuf = (float*)alloc((size_t)T_ * K_ * 4);
    int*      maskI = (int*)alloc((size_t)T_ * 4);
    float*    invc  = (float*)alloc((size_t)T_ * 4);
    int*      valid = (int*)alloc((size_t)T_ * 4);
    int*      idx   = (int*)alloc((size_t)T_ * 4);
    int*      Tc    = (int*)alloc(256);
    int*      mode  = (int*)alloc(256);
    float*    mixed = (float*)hidc;   // aliases hidc (dead after gemm2)

    hipLaunchKernelGGL(detect_kernel, dim3(1), dim3(256), 0, stream,
                       (const unsigned char*)h, (const unsigned char*)mraw, mode);
    hipLaunchKernelGGL(mask_prep_kernel, dim3(1), dim3(256), 0, stream,
                       mraw, mode, maskI, idx, Tc, invc, valid);
    hipLaunchKernelGGL(conv_hc_kernel, dim3(T_ * D_ / 8 / 256), dim3(256), 0, stream,
                       h, mode, idx, Tc, hbfc);
    hipLaunchKernelGGL(router_kernel, dim3(T_), dim3(256), 0, stream,
                       h, Wr, br, mode, maskI, wRbuf);
    hipLaunchKernelGGL(transpose_kernel, dim3(D_ / 32, F_ / 32, K_), dim3(256), 0, stream,
                       W1, W1t, D_, F_, mode);
    hipLaunchKernelGGL(transpose_kernel, dim3(F_ / 32, D_ / 32, K_), dim3(256), 0, stream,
                       W2, W2t, F_, D_, mode);
    hipLaunchKernelGGL(gemm1_kernel, dim3(T_ / 128, K_ * F_ / 128), dim3(256), 0, stream,
                       hbfc, W1t, b1, mode, Tc, hidc);
    hipLaunchKernelGGL(gemm2_kernel, dim3(T_ / 128, D_ / 128, K_), dim3(256), 0, stream,
                       hidc, W2t, b2, mode, Tc, idx, eo);
    hipLaunchKernelGGL(window_all_kernel, dim3(S_ / WSEG, B_), dim3(256), 0, stream,
                       eo, wRbuf, maskI, invc, mixed);
    hipLaunchKernelGGL(ln_kernel, dim3(T_), dim3(256), 0, stream,
                       mixed, valid, mode, d_out);
}

// Round 7
// 447.168 us; speedup vs baseline: 1.0380x; 1.0380x over previous
//
#include <hip/hip_runtime.h>
#include <math.h>

// Problem constants: B=2, S=2048, D=2048, K=8, F=D/4=512, R=8
#define B_ 2
#define S_ 2048
#define T_ (B_*S_)
#define D_ 2048
#define K_ 8
#define F_ 512
#define R_ 8
#define WSEG 16   // s-segment per window block

typedef unsigned short ushort_t;
typedef __attribute__((__ext_vector_type__(8))) __bf16 bf16x8;
typedef __attribute__((__ext_vector_type__(4))) float f32x4;

__device__ __forceinline__ float bf2f(ushort_t u) {
    return __uint_as_float(((unsigned int)u) << 16);
}
__device__ __forceinline__ ushort_t f2bf(float f) {
    unsigned int u = __float_as_uint(f);
    unsigned int r = u + 0x7FFFu + ((u >> 16) & 1u);
    return (ushort_t)(r >> 16);
}
__device__ __forceinline__ float loadF(const void* p, size_t idx, int f32m) {
    if (f32m) return ((const float*)p)[idx];
    return bf2f(((const ushort_t*)p)[idx]);
}

// 16B global->LDS staging; async direct-to-LDS when available (m97: 1.69x).
#if defined(__has_builtin)
#if __has_builtin(__builtin_amdgcn_global_load_lds)
#define ASYNC_LDS 1
#endif
#endif
__device__ __forceinline__ void ld16_lds(void* l, const void* g) {
#ifdef ASYNC_LDS
    __builtin_amdgcn_global_load_lds((const __attribute__((address_space(1))) unsigned int*)g,
                                     (__attribute__((address_space(3))) unsigned int*)l,
                                     16, 0, 0);
#else
    *(uint4*)l = *(const uint4*)g;
#endif
}

// ---------------- layout/dtype detection ----------------
__global__ void detect_kernel(const unsigned char* __restrict__ hraw,
                              const unsigned char* __restrict__ mraw,
                              int* __restrict__ modePtr) {
    __shared__ int has_non01, has_nz123, has_3F1, outlier;
    if (threadIdx.x == 0) { has_non01 = 0; has_nz123 = 0; has_3F1 = 0; outlier = 0; }
    __syncthreads();
    int a = 0, b = 0, c = 0, o = 0;
    for (int i = threadIdx.x; i < 4096; i += 256) {
        unsigned char v = mraw[i];
        if (v > 1) a = 1;
        if ((i & 3) != 0 && v != 0) b = 1;
        if ((i & 3) == 1 && v >= 2) c = 1;
        if ((i & 3) == 1) {
            unsigned char hb = hraw[i] & 0x7F;
            if (hb < 0x30 || hb > 0x47) o++;
        }
    }
    if (a) atomicOr(&has_non01, 1);
    if (b) atomicOr(&has_nz123, 1);
    if (c) atomicOr(&has_3F1, 1);
    if (o) atomicAdd(&outlier, o);
    __syncthreads();
    if (threadIdx.x == 0) {
        int mode;
        if (!has_non01) mode = has_nz123 ? 0 : 1;
        else            mode = has_3F1 ? 2 : 3;
        modePtr[0] = mode;
        modePtr[1] = (outlier > 256) ? 1 : 0;
    }
}

// ---------------- mask prep: maskI, unmasked-index compaction, invcnt, valid ----------------
__global__ __launch_bounds__(256) void mask_prep_kernel(const void* __restrict__ raw,
                                                        const int* __restrict__ modePtr,
                                                        int* __restrict__ maskI,
                                                        int* __restrict__ idx,
                                                        int* __restrict__ TcPtr,
                                                        float* __restrict__ invcnt,
                                                        int* __restrict__ valid) {
    __shared__ int sm[T_];        // 16 KB
    __shared__ int cnts[257];
    const int tid = threadIdx.x;
    const int mode = modePtr[0];
    for (int t = tid; t < T_; t += 256) {
        int m;
        if (mode == 0)      m = ((const unsigned char*)raw)[t] != 0;
        else if (mode == 1) m = ((const int*)raw)[t] != 0;
        else if (mode == 2) m = ((const ushort_t*)raw)[t] != 0;
        else                m = ((const unsigned int*)raw)[t] != 0;
        sm[t] = m;
        maskI[t] = m;
    }
    __syncthreads();
    const int base = tid * 16;
    int cnt = 0;
#pragma unroll
    for (int u = 0; u < 16; ++u) cnt += (sm[base + u] == 0);
    cnts[tid] = cnt;
    __syncthreads();
    if (tid == 0) {
        int run = 0;
        for (int i = 0; i < 256; ++i) { int c = cnts[i]; cnts[i] = run; run += c; }
        cnts[256] = run;
    }
    __syncthreads();
    int run = cnts[tid];
#pragma unroll
    for (int u = 0; u < 16; ++u) {
        int t = base + u;
        if (!sm[t]) idx[run++] = t;
    }
    const int Tc = cnts[256];
    for (int i = Tc + tid; i < T_; i += 256) idx[i] = T_;   // sentinel
    if (tid == 0) TcPtr[0] = Tc;
    for (int t = tid; t < T_; t += 256) {
        int b = t >> 11, s = t & (S_ - 1);
        int lo = s - R_; if (lo < 0) lo = 0;
        int hi = s + R_; if (hi > S_ - 1) hi = S_ - 1;
        int c = 0;
        for (int sp = lo; sp <= hi; ++sp) c += (sm[b * S_ + sp] == 0);
        c -= (sm[t] == 0);
        invcnt[t] = 1.0f / fmaxf((float)c, 1.0f);
        valid[t] = (sm[t] && c > 0) ? 1 : 0;
    }
}

// ---------------- compact h rows -> bf16 ----------------
__global__ __launch_bounds__(256) void conv_hc_kernel(const void* __restrict__ hraw,
                                                      const int* __restrict__ modePtr,
                                                      const int* __restrict__ idx,
                                                      const int* __restrict__ TcPtr,
                                                      ushort_t* __restrict__ hbfc) {
    int gid = blockIdx.x * 256 + threadIdx.x;
    int i = gid >> 8;
    if (i >= *TcPtr) return;
    int col = (gid & 255) * 8;
    size_t src = (size_t)idx[i] * D_ + col;
    size_t dst = (size_t)i * D_ + col;
    if (modePtr[1]) {
        const float* p = (const float*)hraw + src;
        float4 a = *(const float4*)p;
        float4 b = *(const float4*)(p + 4);
        uint4 o;
        o.x = (unsigned)f2bf(a.x) | ((unsigned)f2bf(a.y) << 16);
        o.y = (unsigned)f2bf(a.z) | ((unsigned)f2bf(a.w) << 16);
        o.z = (unsigned)f2bf(b.x) | ((unsigned)f2bf(b.y) << 16);
        o.w = (unsigned)f2bf(b.z) | ((unsigned)f2bf(b.w) << 16);
        *(uint4*)&hbfc[dst] = o;
    } else {
        *(uint4*)&hbfc[dst] = *(const uint4*)((const ushort_t*)hraw + src);
    }
}

// ---------------- router: softmax(h @ W_route + b_route), masked tokens only ----------------
__global__ __launch_bounds__(256) void router_kernel(const void* __restrict__ hraw,
                                                     const void* __restrict__ Wr,
                                                     const void* __restrict__ br,
                                                     const int* __restrict__ modePtr,
                                                     const int* __restrict__ maskI,
                                                     float* __restrict__ wout) {
    int t = blockIdx.x;
    if (!maskI[t]) return;
    int f32m = modePtr[1];
    float p[8];
#pragma unroll
    for (int k = 0; k < 8; ++k) p[k] = 0.f;
    if (f32m) {
        for (int d = threadIdx.x; d < D_; d += 256) {
            float hv = ((const float*)hraw)[(size_t)t * D_ + d];
            const float* wrow = (const float*)Wr + (size_t)d * 8;
            float4 q0 = *(const float4*)wrow;
            float4 q1 = *(const float4*)(wrow + 4);
            p[0] += hv * q0.x; p[1] += hv * q0.y; p[2] += hv * q0.z; p[3] += hv * q0.w;
            p[4] += hv * q1.x; p[5] += hv * q1.y; p[6] += hv * q1.z; p[7] += hv * q1.w;
        }
    } else {
        const ushort_t* Wrb = (const ushort_t*)Wr;
        for (int d = threadIdx.x; d < D_; d += 256) {
            float hv = bf2f(((const ushort_t*)hraw)[(size_t)t * D_ + d]);
            uint4 q = *(const uint4*)&Wrb[(size_t)d * 8];
            p[0] += hv * __uint_as_float(q.x << 16);
            p[1] += hv * __uint_as_float(q.x & 0xFFFF0000u);
            p[2] += hv * __uint_as_float(q.y << 16);
            p[3] += hv * __uint_as_float(q.y & 0xFFFF0000u);
            p[4] += hv * __uint_as_float(q.z << 16);
            p[5] += hv * __uint_as_float(q.z & 0xFFFF0000u);
            p[6] += hv * __uint_as_float(q.w << 16);
            p[7] += hv * __uint_as_float(q.w & 0xFFFF0000u);
        }
    }
#pragma unroll
    for (int off = 32; off; off >>= 1)
#pragma unroll
        for (int k = 0; k < 8; ++k) p[k] += __shfl_down(p[k], off);
    __shared__ float sm[4][8];
    int w = threadIdx.x >> 6, lane = threadIdx.x & 63;
    if (lane == 0)
#pragma unroll
        for (int k = 0; k < 8; ++k) sm[w][k] = p[k];
    __syncthreads();
    if (threadIdx.x == 0) {
        float lg[8];
        float mx = -1e30f;
#pragma unroll
        for (int k = 0; k < 8; ++k) {
            lg[k] = sm[0][k] + sm[1][k] + sm[2][k] + sm[3][k] + loadF(br, k, f32m);
            mx = fmaxf(mx, lg[k]);
        }
        float ssum = 0.f;
#pragma unroll
        for (int k = 0; k < 8; ++k) { lg[k] = __expf(lg[k] - mx); ssum += lg[k]; }
        float inv = 1.0f / ssum;
#pragma unroll
        for (int k = 0; k < 8; ++k) wout[t * 8 + k] = lg[k] * inv;
    }
}

// ---------------- dtype-aware 32x32 transpose of expert slice (z=expert) ----------------
__global__ __launch_bounds__(256) void transpose_kernel(const void* __restrict__ in,
                                                        ushort_t* __restrict__ op,
                                                        int rows, int cols,
                                                        const int* __restrict__ modePtr) {
    __shared__ ushort_t tile[32][33];
    int f32m = modePtr[1];
    int kexp = blockIdx.z;
    size_t base = (size_t)kexp * rows * cols;
    ushort_t* ob = op + (size_t)kexp * rows * cols;
    int r0 = blockIdx.x * 32, c0 = blockIdx.y * 32;
    int tx = threadIdx.x & 31, ty = threadIdx.x >> 5;
#pragma unroll
    for (int i = 0; i < 4; ++i) {
        int r = ty + i * 8;
        tile[r][tx] = f2bf(loadF(in, base + (size_t)(r0 + r) * cols + c0 + tx, f32m));
    }
    __syncthreads();
#pragma unroll
    for (int i = 0; i < 4; ++i) {
        int c = ty + i * 8;
        ob[(size_t)(c0 + c) * rows + r0 + tx] = tile[tx][c];
    }
}

// ---------------- GEMM1 (experts merged into N; 64x128 tile, BK=64, single buffer) ----------------
// C[i][n] = gelu(hbfc @ W1t^T + b1), M=Tc, N=K_*F_=4096, K=D_.
// Grid (T_/64, 32): ~1024 active blocks -> 4/CU, 16 waves/CU.
__global__ __launch_bounds__(256) void gemm1_kernel(const ushort_t* __restrict__ hbfc,
                                                    const ushort_t* __restrict__ W1t,
                                                    const void* __restrict__ b1,
                                                    const int* __restrict__ modePtr,
                                                    const int* __restrict__ TcPtr,
                                                    ushort_t* __restrict__ hidc) {
    const int bm = blockIdx.x;
    if (bm * 64 >= *TcPtr) return;   // block-uniform early exit
    __shared__ ushort_t Al[64 * 64];    // 8 KB
    __shared__ ushort_t Bl[128 * 64];   // 16 KB
    const int f32m = modePtr[1];
    const int bn = blockIdx.y;
    const int tid = threadIdx.x;
    const int lane = tid & 63, w = tid >> 6;
    const int lm = lane & 15, quad = lane >> 4;
    const int wm = (w >> 1) * 32, wn = (w & 1) * 64;
    const ushort_t* Ab = hbfc + (size_t)(bm * 64) * D_;
    const ushort_t* Bb = W1t + (size_t)(bn * 128) * D_;
    f32x4 acc[2][4];
    const f32x4 zz = {0.f, 0.f, 0.f, 0.f};
#pragma unroll
    for (int i = 0; i < 2; ++i)
#pragma unroll
        for (int j = 0; j < 4; ++j) acc[i][j] = zz;
    const int r0 = tid >> 3, c0 = (tid & 7) * 8;   // 32 rows/pass, 16B/thread
    for (int kt = 0; kt < D_ / 64; ++kt) {
        const int kb = kt * 64;
        __syncthreads();
        ld16_lds(&Al[r0 * 64 + c0],        &Ab[(size_t)r0 * D_ + kb + c0]);
        ld16_lds(&Al[(r0 + 32) * 64 + c0], &Ab[(size_t)(r0 + 32) * D_ + kb + c0]);
        ld16_lds(&Bl[r0 * 64 + c0],        &Bb[(size_t)r0 * D_ + kb + c0]);
        ld16_lds(&Bl[(r0 + 32) * 64 + c0], &Bb[(size_t)(r0 + 32) * D_ + kb + c0]);
        ld16_lds(&Bl[(r0 + 64) * 64 + c0], &Bb[(size_t)(r0 + 64) * D_ + kb + c0]);
        ld16_lds(&Bl[(r0 + 96) * 64 + c0], &Bb[(size_t)(r0 + 96) * D_ + kb + c0]);
        __syncthreads();
#pragma unroll
        for (int kk = 0; kk < 2; ++kk) {
            bf16x8 af[2], bfr[4];
#pragma unroll
            for (int i = 0; i < 2; ++i)
                af[i] = *(const bf16x8*)&Al[(wm + i * 16 + lm) * 64 + kk * 32 + quad * 8];
#pragma unroll
            for (int j = 0; j < 4; ++j)
                bfr[j] = *(const bf16x8*)&Bl[(wn + j * 16 + lm) * 64 + kk * 32 + quad * 8];
#pragma unroll
            for (int i = 0; i < 2; ++i)
#pragma unroll
                for (int j = 0; j < 4; ++j)
                    acc[i][j] = __builtin_amdgcn_mfma_f32_16x16x32_bf16(af[i], bfr[j], acc[i][j], 0, 0, 0);
        }
    }
#pragma unroll
    for (int j = 0; j < 4; ++j) {
        int n = bn * 128 + wn + j * 16 + lm;
        int kexp = n >> 9, fg = n & 511;
        float bias = loadF(b1, (size_t)n, f32m);
#pragma unroll
        for (int i = 0; i < 2; ++i) {
            int mb = bm * 64 + wm + i * 16 + quad * 4;
#pragma unroll
            for (int v = 0; v < 4; ++v) {
                float x = acc[i][j][v] + bias;
                float g = 0.5f * x * (1.0f + erff(x * 0.70710678118654752f));
                hidc[(size_t)kexp * T_ * F_ + (size_t)(mb + v) * F_ + fg] = f2bf(g);
            }
        }
    }
}

// ---------------- GEMM2 (z=expert; 64x128 tile, BK=64, single buffer, scatter) ----------------
// Grid (T_/64, D_/128, K_): ~4096 active blocks.
__global__ __launch_bounds__(256) void gemm2_kernel(const ushort_t* __restrict__ hidc,
                                                    const ushort_t* __restrict__ W2t,
                                                    const void* __restrict__ b2,
                                                    const int* __restrict__ modePtr,
                                                    const int* __restrict__ TcPtr,
                                                    const int* __restrict__ idx,
                                                    ushort_t* __restrict__ eo) {
    const int bm = blockIdx.x;
    if (bm * 64 >= *TcPtr) return;
    __shared__ ushort_t Al[64 * 64];    // 8 KB
    __shared__ ushort_t Bl[128 * 64];   // 16 KB
    __shared__ int sidx[64];
    const int f32m = modePtr[1];
    const int kexp = blockIdx.z;
    const int bn = blockIdx.y;
    const int tid = threadIdx.x;
    if (tid < 64) sidx[tid] = idx[bm * 64 + tid];
    const int lane = tid & 63, w = tid >> 6;
    const int lm = lane & 15, quad = lane >> 4;
    const int wm = (w >> 1) * 32, wn = (w & 1) * 64;
    const ushort_t* Ab = hidc + (size_t)kexp * T_ * F_ + (size_t)(bm * 64) * F_;
    const ushort_t* Bb = W2t + (size_t)kexp * D_ * F_ + (size_t)(bn * 128) * F_;
    f32x4 acc[2][4];
    const f32x4 zz = {0.f, 0.f, 0.f, 0.f};
#pragma unroll
    for (int i = 0; i < 2; ++i)
#pragma unroll
        for (int j = 0; j < 4; ++j) acc[i][j] = zz;
    const int r0 = tid >> 3, c0 = (tid & 7) * 8;
    for (int kt = 0; kt < F_ / 64; ++kt) {
        const int kb = kt * 64;
        __syncthreads();
        ld16_lds(&Al[r0 * 64 + c0],        &Ab[(size_t)r0 * F_ + kb + c0]);
        ld16_lds(&Al[(r0 + 32) * 64 + c0], &Ab[(size_t)(r0 + 32) * F_ + kb + c0]);
        ld16_lds(&Bl[r0 * 64 + c0],        &Bb[(size_t)r0 * F_ + kb + c0]);
        ld16_lds(&Bl[(r0 + 32) * 64 + c0], &Bb[(size_t)(r0 + 32) * F_ + kb + c0]);
        ld16_lds(&Bl[(r0 + 64) * 64 + c0], &Bb[(size_t)(r0 + 64) * F_ + kb + c0]);
        ld16_lds(&Bl[(r0 + 96) * 64 + c0], &Bb[(size_t)(r0 + 96) * F_ + kb + c0]);
        __syncthreads();
#pragma unroll
        for (int kk = 0; kk < 2; ++kk) {
            bf16x8 af[2], bfr[4];
#pragma unroll
            for (int i = 0; i < 2; ++i)
                af[i] = *(const bf16x8*)&Al[(wm + i * 16 + lm) * 64 + kk * 32 + quad * 8];
#pragma unroll
            for (int j = 0; j < 4; ++j)
                bfr[j] = *(const bf16x8*)&Bl[(wn + j * 16 + lm) * 64 + kk * 32 + quad * 8];
#pragma unroll
            for (int i = 0; i < 2; ++i)
#pragma unroll
                for (int j = 0; j < 4; ++j)
                    acc[i][j] = __builtin_amdgcn_mfma_f32_16x16x32_bf16(af[i], bfr[j], acc[i][j], 0, 0, 0);
        }
    }
#pragma unroll
    for (int j = 0; j < 4; ++j) {
        int dg = bn * 128 + wn + j * 16 + lm;
        float bias = loadF(b2, (size_t)kexp * D_ + dg, f32m);
#pragma unroll
        for (int i = 0; i < 2; ++i) {
            int lr = wm + i * 16 + quad * 4;
#pragma unroll
            for (int v = 0; v < 4; ++v) {
                int tok = sidx[lr + v];   // sentinel T_ for padded rows
                float x = acc[i][j][v] + bias;
                eo[((size_t)tok * K_ + kexp) * D_ + dg] = f2bf(x);
            }
        }
    }
}

// ---------------- sliding window over all experts + routing mix (skips masked rows) ----------------
__device__ __forceinline__ void acc8add(float* run, const ushort_t* p) {
    const uint4 q = *(const uint4*)p;
    run[0] += __uint_as_float(q.x << 16);
    run[1] += __uint_as_float(q.x & 0xFFFF0000u);
    run[2] += __uint_as_float(q.y << 16);
    run[3] += __uint_as_float(q.y & 0xFFFF0000u);
    run[4] += __uint_as_float(q.z << 16);
    run[5] += __uint_as_float(q.z & 0xFFFF0000u);
    run[6] += __uint_as_float(q.w << 16);
    run[7] += __uint_as_float(q.w & 0xFFFF0000u);
}
__device__ __forceinline__ void acc8sub(float* run, const ushort_t* p) {
    const uint4 q = *(const uint4*)p;
    run[0] -= __uint_as_float(q.x << 16);
    run[1] -= __uint_as_float(q.x & 0xFFFF0000u);
    run[2] -= __uint_as_float(q.y << 16);
    run[3] -= __uint_as_float(q.y & 0xFFFF0000u);
    run[4] -= __uint_as_float(q.z << 16);
    run[5] -= __uint_as_float(q.z & 0xFFFF0000u);
    run[6] -= __uint_as_float(q.w << 16);
    run[7] -= __uint_as_float(q.w & 0xFFFF0000u);
}

__global__ __launch_bounds__(256) void window_all_kernel(const ushort_t* __restrict__ eo,
                                                         const float* __restrict__ wR,
                                                         const int* __restrict__ maskI,
                                                         const float* __restrict__ invcnt,
                                                         float* __restrict__ mixed) {
    const int b = blockIdx.y;
    const int s0 = blockIdx.x * WSEG;
    const int d0 = threadIdx.x * 8;
    float run[K_][8];
#pragma unroll
    for (int k = 0; k < K_; ++k)
#pragma unroll
        for (int j = 0; j < 8; ++j) run[k][j] = 0.f;
    int lo = s0 - R_; if (lo < 0) lo = 0;
    for (int sp = lo; sp < s0 + R_; ++sp) {
        if (maskI[b * S_ + sp]) continue;
        const ushort_t* row = &eo[(size_t)(b * S_ + sp) * K_ * D_ + d0];
#pragma unroll
        for (int k = 0; k < K_; ++k) acc8add(run[k], row + (size_t)k * D_);
    }
    for (int s = s0; s < s0 + WSEG; ++s) {
        const int t = b * S_ + s;
        if (s + R_ < S_ && !maskI[t + R_]) {
            const ushort_t* row = &eo[(size_t)(t + R_) * K_ * D_ + d0];
#pragma unroll
            for (int k = 0; k < K_; ++k) acc8add(run[k], row + (size_t)k * D_);
        }
        if (maskI[t]) {
            float ic = invcnt[t];
            float o[8];
#pragma unroll
            for (int j = 0; j < 8; ++j) o[j] = 0.f;
#pragma unroll
            for (int k = 0; k < K_; ++k) {
                float wk = wR[t * K_ + k] * ic;
#pragma unroll
                for (int j = 0; j < 8; ++j) o[j] += wk * run[k][j];
            }
            float4 o0 = {o[0], o[1], o[2], o[3]};
            float4 o1 = {o[4], o[5], o[6], o[7]};
            *(float4*)&mixed[(size_t)t * D_ + d0]     = o0;
            *(float4*)&mixed[(size_t)t * D_ + d0 + 4] = o1;
        }
        if (s - R_ >= 0 && !maskI[t - R_]) {
            const ushort_t* row = &eo[(size_t)(t - R_) * K_ * D_ + d0];
#pragma unroll
            for (int k = 0; k < K_; ++k) acc8sub(run[k], row + (size_t)k * D_);
        }
    }
}

// ---------------- LayerNorm + validity mask; dtype-aware output ----------------
__global__ __launch_bounds__(256) void ln_kernel(const float* __restrict__ mixed,
                                                 const int* __restrict__ valid,
                                                 const int* __restrict__ modePtr,
                                                 void* __restrict__ out) {
    const int t = blockIdx.x;
    const int tid = threadIdx.x;
    const int f32m = modePtr[1];
    if (!valid[t]) {
        if (f32m) {
            float4 z = {0.f, 0.f, 0.f, 0.f};
            float* op = (float*)out + (size_t)t * D_ + tid * 8;
            *(float4*)op = z; *(float4*)(op + 4) = z;
        } else {
            uint4 z = {0u, 0u, 0u, 0u};
            *(uint4*)((ushort_t*)out + (size_t)t * D_ + tid * 8) = z;
        }
        return;
    }
    float4 a = *(const float4*)&mixed[(size_t)t * D_ + tid * 8];
    float4 c = *(const float4*)&mixed[(size_t)t * D_ + tid * 8 + 4];
    float xs[8] = {a.x, a.y, a.z, a.w, c.x, c.y, c.z, c.w};
    float s1 = 0.f, s2 = 0.f;
#pragma unroll
    for (int j = 0; j < 8; ++j) { s1 += xs[j]; s2 += xs[j] * xs[j]; }
#pragma unroll
    for (int off = 32; off; off >>= 1) { s1 += __shfl_down(s1, off); s2 += __shfl_down(s2, off); }
    __shared__ float sm[8];
    int w = tid >> 6;
    if ((tid & 63) == 0) { sm[w * 2] = s1; sm[w * 2 + 1] = s2; }
    __syncthreads();
    float ts1 = sm[0] + sm[2] + sm[4] + sm[6];
    float ts2 = sm[1] + sm[3] + sm[5] + sm[7];
    float mu = ts1 * (1.0f / D_);
    float var = fmaxf(ts2 * (1.0f / D_) - mu * mu, 0.0f);
    float inv = rsqrtf(var + 1e-5f);
    if (f32m) {
        float* op = (float*)out + (size_t)t * D_ + tid * 8;
        float4 o0 = {(xs[0] - mu) * inv, (xs[1] - mu) * inv, (xs[2] - mu) * inv, (xs[3] - mu) * inv};
        float4 o1 = {(xs[4] - mu) * inv, (xs[5] - mu) * inv, (xs[6] - mu) * inv, (xs[7] - mu) * inv};
        *(float4*)op = o0; *(float4*)(op + 4) = o1;
    } else {
        ushort_t ob[8];
#pragma unroll
        for (int j = 0; j < 8; ++j) ob[j] = f2bf((xs[j] - mu) * inv);
        uint4 o;
        o.x = (unsigned)ob[0] | ((unsigned)ob[1] << 16);
        o.y = (unsigned)ob[2] | ((unsigned)ob[3] << 16);
        o.z = (unsigned)ob[4] | ((unsigned)ob[5] << 16);
        o.w = (unsigned)ob[6] | ((unsigned)ob[7] << 16);
        *(uint4*)((ushort_t*)out + (size_t)t * D_ + tid * 8) = o;
    }
}

extern "C" void kernel_launch(void* const* d_in, const int* in_sizes, int n_in,
                              void* d_out, int out_size, void* d_ws, size_t ws_size,
                              hipStream_t stream) {
    const void* h    = d_in[0];
    const void* mraw = d_in[1];
    const void* Wr   = d_in[2];
    const void* br   = d_in[3];
    const void* W1   = d_in[4];
    const void* b1   = d_in[5];
    const void* W2   = d_in[6];
    const void* b2   = d_in[7];
    (void)in_sizes; (void)n_in; (void)out_size; (void)ws_size;

    char* ws = (char*)d_ws;
    size_t off = 0;
    auto alloc = [&](size_t bytes) -> void* {
        void* p = ws + off;
        off += (bytes + 255) & ~(size_t)255;
        return p;
    };
    ushort_t* hbfc  = (ushort_t*)alloc((size_t)T_ * D_ * 2);              // 16.8 MB
    ushort_t* W1t   = (ushort_t*)alloc((size_t)K_ * F_ * D_ * 2);         // 16.8 MB [K][F][D] == B^T[4096][2048]
    ushort_t* W2t   = (ushort_t*)alloc((size_t)K_ * D_ * F_ * 2);         // 16.8 MB [K][D][F]
    ushort_t* hidc  = (ushort_t*)alloc((size_t)K_ * T_ * F_ * 2);         // 33.6 MB [K][Tc][F]
    ushort_t* eo    = (ushort_t*)alloc(((size_t)T_ + 1) * K_ * D_ * 2);   // 134 MB + sentinel row
    float*    wRbuf = (float*)alloc((size_t)T_ * K_ * 4);
    int*      maskI = (int*)alloc((size_t)T_ * 4);
    float*    invc  = (float*)alloc((size_t)T_ * 4);
    int*      valid = (int*)alloc((size_t)T_ * 4);
    int*      idx   = (int*)alloc((size_t)T_ * 4);
    int*      Tc    = (int*)alloc(256);
    int*      mode  = (int*)alloc(256);
    float*    mixed = (float*)hidc;   // aliases hidc (dead after gemm2)

    hipLaunchKernelGGL(detect_kernel, dim3(1), dim3(256), 0, stream,
                       (const unsigned char*)h, (const unsigned char*)mraw, mode);
    hipLaunchKernelGGL(mask_prep_kernel, dim3(1), dim3(256), 0, stream,
                       mraw, mode, maskI, idx, Tc, invc, valid);
    hipLaunchKernelGGL(conv_hc_kernel, dim3(T_ * D_ / 8 / 256), dim3(256), 0, stream,
                       h, mode, idx, Tc, hbfc);
    hipLaunchKernelGGL(router_kernel, dim3(T_), dim3(256), 0, stream,
                       h, Wr, br, mode, maskI, wRbuf);
    hipLaunchKernelGGL(transpose_kernel, dim3(D_ / 32, F_ / 32, K_), dim3(256), 0, stream,
                       W1, W1t, D_, F_, mode);
    hipLaunchKernelGGL(transpose_kernel, dim3(F_ / 32, D_ / 32, K_), dim3(256), 0, stream,
                       W2, W2t, F_, D_, mode);
    hipLaunchKernelGGL(gemm1_kernel, dim3(T_ / 64, K_ * F_ / 128), dim3(256), 0, stream,
                       hbfc, W1t, b1, mode, Tc, hidc);
    hipLaunchKernelGGL(gemm2_kernel, dim3(T_ / 64, D_ / 128, K_), dim3(256), 0, stream,
                       hidc, W2t, b2, mode, Tc, idx, eo);
    hipLaunchKernelGGL(window_all_kernel, dim3(S_ / WSEG, B_), dim3(256), 0, stream,
                       eo, wRbuf, maskI, invc, mixed);
    hipLaunchKernelGGL(ln_kernel, dim3(T_), dim3(256), 0, stream,
                       mixed, valid, mode, d_out);
}

// Round 8
// 417.295 us; speedup vs baseline: 1.1124x; 1.0716x over previous
//
#include <hip/hip_runtime.h>
#include <math.h>

// Problem constants: B=2, S=2048, D=2048, K=8, F=D/4=512, R=8
#define B_ 2
#define S_ 2048
#define T_ (B_*S_)
#define D_ 2048
#define K_ 8
#define F_ 512
#define R_ 8
#define WSEG 16   // s-segment per window block

typedef unsigned short ushort_t;
typedef __attribute__((__ext_vector_type__(8))) __bf16 bf16x8;
typedef __attribute__((__ext_vector_type__(4))) float f32x4;

__device__ __forceinline__ float bf2f(ushort_t u) {
    return __uint_as_float(((unsigned int)u) << 16);
}
__device__ __forceinline__ ushort_t f2bf(float f) {
    unsigned int u = __float_as_uint(f);
    unsigned int r = u + 0x7FFFu + ((u >> 16) & 1u);
    return (ushort_t)(r >> 16);
}
__device__ __forceinline__ float loadF(const void* p, size_t idx, int f32m) {
    if (f32m) return ((const float*)p)[idx];
    return bf2f(((const ushort_t*)p)[idx]);
}

// 16B global->LDS staging; async direct-to-LDS when available (m97: 1.69x).
#if defined(__has_builtin)
#if __has_builtin(__builtin_amdgcn_global_load_lds)
#define ASYNC_LDS 1
#endif
#endif
__device__ __forceinline__ void ld16_lds(void* l, const void* g) {
#ifdef ASYNC_LDS
    __builtin_amdgcn_global_load_lds((const __attribute__((address_space(1))) unsigned int*)g,
                                     (__attribute__((address_space(3))) unsigned int*)l,
                                     16, 0, 0);
#else
    *(uint4*)l = *(const uint4*)g;
#endif
}

// ---------------- layout/dtype detection ----------------
__global__ void detect_kernel(const unsigned char* __restrict__ hraw,
                              const unsigned char* __restrict__ mraw,
                              int* __restrict__ modePtr) {
    __shared__ int has_non01, has_nz123, has_3F1, outlier;
    if (threadIdx.x == 0) { has_non01 = 0; has_nz123 = 0; has_3F1 = 0; outlier = 0; }
    __syncthreads();
    int a = 0, b = 0, c = 0, o = 0;
    for (int i = threadIdx.x; i < 4096; i += 256) {
        unsigned char v = mraw[i];
        if (v > 1) a = 1;
        if ((i & 3) != 0 && v != 0) b = 1;
        if ((i & 3) == 1 && v >= 2) c = 1;
        if ((i & 3) == 1) {
            unsigned char hb = hraw[i] & 0x7F;
            if (hb < 0x30 || hb > 0x47) o++;
        }
    }
    if (a) atomicOr(&has_non01, 1);
    if (b) atomicOr(&has_nz123, 1);
    if (c) atomicOr(&has_3F1, 1);
    if (o) atomicAdd(&outlier, o);
    __syncthreads();
    if (threadIdx.x == 0) {
        int mode;
        if (!has_non01) mode = has_nz123 ? 0 : 1;
        else            mode = has_3F1 ? 2 : 3;
        modePtr[0] = mode;
        modePtr[1] = (outlier > 256) ? 1 : 0;
    }
}

// ---------------- mask prep: maskI, unmasked-index compaction, invcnt, valid ----------------
__global__ __launch_bounds__(256) void mask_prep_kernel(const void* __restrict__ raw,
                                                        const int* __restrict__ modePtr,
                                                        int* __restrict__ maskI,
                                                        int* __restrict__ idx,
                                                        int* __restrict__ TcPtr,
                                                        float* __restrict__ invcnt,
                                                        int* __restrict__ valid) {
    __shared__ int sm[T_];        // 16 KB
    __shared__ int cnts[257];
    const int tid = threadIdx.x;
    const int mode = modePtr[0];
    for (int t = tid; t < T_; t += 256) {
        int m;
        if (mode == 0)      m = ((const unsigned char*)raw)[t] != 0;
        else if (mode == 1) m = ((const int*)raw)[t] != 0;
        else if (mode == 2) m = ((const ushort_t*)raw)[t] != 0;
        else                m = ((const unsigned int*)raw)[t] != 0;
        sm[t] = m;
        maskI[t] = m;
    }
    __syncthreads();
    const int base = tid * 16;
    int cnt = 0;
#pragma unroll
    for (int u = 0; u < 16; ++u) cnt += (sm[base + u] == 0);
    cnts[tid] = cnt;
    __syncthreads();
    if (tid == 0) {
        int run = 0;
        for (int i = 0; i < 256; ++i) { int c = cnts[i]; cnts[i] = run; run += c; }
        cnts[256] = run;
    }
    __syncthreads();
    int run = cnts[tid];
#pragma unroll
    for (int u = 0; u < 16; ++u) {
        int t = base + u;
        if (!sm[t]) idx[run++] = t;
    }
    const int Tc = cnts[256];
    for (int i = Tc + tid; i < T_; i += 256) idx[i] = T_;   // sentinel
    if (tid == 0) TcPtr[0] = Tc;
    for (int t = tid; t < T_; t += 256) {
        int b = t >> 11, s = t & (S_ - 1);
        int lo = s - R_; if (lo < 0) lo = 0;
        int hi = s + R_; if (hi > S_ - 1) hi = S_ - 1;
        int c = 0;
        for (int sp = lo; sp <= hi; ++sp) c += (sm[b * S_ + sp] == 0);
        c -= (sm[t] == 0);
        invcnt[t] = 1.0f / fmaxf((float)c, 1.0f);
        valid[t] = (sm[t] && c > 0) ? 1 : 0;
    }
}

// ---------------- compact h rows -> bf16 ----------------
__global__ __launch_bounds__(256) void conv_hc_kernel(const void* __restrict__ hraw,
                                                      const int* __restrict__ modePtr,
                                                      const int* __restrict__ idx,
                                                      const int* __restrict__ TcPtr,
                                                      ushort_t* __restrict__ hbfc) {
    int gid = blockIdx.x * 256 + threadIdx.x;
    int i = gid >> 8;
    if (i >= *TcPtr) return;
    int col = (gid & 255) * 8;
    size_t src = (size_t)idx[i] * D_ + col;
    size_t dst = (size_t)i * D_ + col;
    if (modePtr[1]) {
        const float* p = (const float*)hraw + src;
        float4 a = *(const float4*)p;
        float4 b = *(const float4*)(p + 4);
        uint4 o;
        o.x = (unsigned)f2bf(a.x) | ((unsigned)f2bf(a.y) << 16);
        o.y = (unsigned)f2bf(a.z) | ((unsigned)f2bf(a.w) << 16);
        o.z = (unsigned)f2bf(b.x) | ((unsigned)f2bf(b.y) << 16);
        o.w = (unsigned)f2bf(b.z) | ((unsigned)f2bf(b.w) << 16);
        *(uint4*)&hbfc[dst] = o;
    } else {
        *(uint4*)&hbfc[dst] = *(const uint4*)((const ushort_t*)hraw + src);
    }
}

// ---------------- router: softmax(h @ W_route + b_route), masked tokens only ----------------
__global__ __launch_bounds__(256) void router_kernel(const void* __restrict__ hraw,
                                                     const void* __restrict__ Wr,
                                                     const void* __restrict__ br,
                                                     const int* __restrict__ modePtr,
                                                     const int* __restrict__ maskI,
                                                     float* __restrict__ wout) {
    int t = blockIdx.x;
    if (!maskI[t]) return;
    int f32m = modePtr[1];
    float p[8];
#pragma unroll
    for (int k = 0; k < 8; ++k) p[k] = 0.f;
    if (f32m) {
        for (int d = threadIdx.x; d < D_; d += 256) {
            float hv = ((const float*)hraw)[(size_t)t * D_ + d];
            const float* wrow = (const float*)Wr + (size_t)d * 8;
            float4 q0 = *(const float4*)wrow;
            float4 q1 = *(const float4*)(wrow + 4);
            p[0] += hv * q0.x; p[1] += hv * q0.y; p[2] += hv * q0.z; p[3] += hv * q0.w;
            p[4] += hv * q1.x; p[5] += hv * q1.y; p[6] += hv * q1.z; p[7] += hv * q1.w;
        }
    } else {
        const ushort_t* Wrb = (const ushort_t*)Wr;
        for (int d = threadIdx.x; d < D_; d += 256) {
            float hv = bf2f(((const ushort_t*)hraw)[(size_t)t * D_ + d]);
            uint4 q = *(const uint4*)&Wrb[(size_t)d * 8];
            p[0] += hv * __uint_as_float(q.x << 16);
            p[1] += hv * __uint_as_float(q.x & 0xFFFF0000u);
            p[2] += hv * __uint_as_float(q.y << 16);
            p[3] += hv * __uint_as_float(q.y & 0xFFFF0000u);
            p[4] += hv * __uint_as_float(q.z << 16);
            p[5] += hv * __uint_as_float(q.z & 0xFFFF0000u);
            p[6] += hv * __uint_as_float(q.w << 16);
            p[7] += hv * __uint_as_float(q.w & 0xFFFF0000u);
        }
    }
#pragma unroll
    for (int off = 32; off; off >>= 1)
#pragma unroll
        for (int k = 0; k < 8; ++k) p[k] += __shfl_down(p[k], off);
    __shared__ float sm[4][8];
    int w = threadIdx.x >> 6, lane = threadIdx.x & 63;
    if (lane == 0)
#pragma unroll
        for (int k = 0; k < 8; ++k) sm[w][k] = p[k];
    __syncthreads();
    if (threadIdx.x == 0) {
        float lg[8];
        float mx = -1e30f;
#pragma unroll
        for (int k = 0; k < 8; ++k) {
            lg[k] = sm[0][k] + sm[1][k] + sm[2][k] + sm[3][k] + loadF(br, k, f32m);
            mx = fmaxf(mx, lg[k]);
        }
        float ssum = 0.f;
#pragma unroll
        for (int k = 0; k < 8; ++k) { lg[k] = __expf(lg[k] - mx); ssum += lg[k]; }
        float inv = 1.0f / ssum;
#pragma unroll
        for (int k = 0; k < 8; ++k) wout[t * 8 + k] = lg[k] * inv;
    }
}

// ---------------- dtype-aware 32x32 transpose of expert slice (z=expert) ----------------
__global__ __launch_bounds__(256) void transpose_kernel(const void* __restrict__ in,
                                                        ushort_t* __restrict__ op,
                                                        int rows, int cols,
                                                        const int* __restrict__ modePtr) {
    __shared__ ushort_t tile[32][33];
    int f32m = modePtr[1];
    int kexp = blockIdx.z;
    size_t base = (size_t)kexp * rows * cols;
    ushort_t* ob = op + (size_t)kexp * rows * cols;
    int r0 = blockIdx.x * 32, c0 = blockIdx.y * 32;
    int tx = threadIdx.x & 31, ty = threadIdx.x >> 5;
#pragma unroll
    for (int i = 0; i < 4; ++i) {
        int r = ty + i * 8;
        tile[r][tx] = f2bf(loadF(in, base + (size_t)(r0 + r) * cols + c0 + tx, f32m));
    }
    __syncthreads();
#pragma unroll
    for (int i = 0; i < 4; ++i) {
        int c = ty + i * 8;
        ob[(size_t)(c0 + c) * rows + r0 + tx] = tile[tx][c];
    }
}

// ==== XOR-swizzled LDS layout for GEMM staging ====
// Row r's LDS octet-slot s holds GLOBAL octet (s ^ (r&7)).
// Write: lane covers (row r0, slot s0=tid&7) at fixed LDS addr tid*16 per
//   wave (async-LDS legal); fetches global col ((s0^(r0&7))*8).
// Read: global octet g of row rr lives at LDS slot g^(rr&7).
// Result: fragment reads hit all 32 banks, 2 lanes/bank (free — m136).

// ---------------- GEMM1 (experts merged into N; 64x128 tile, BK=64, swizzled) ----------------
__global__ __launch_bounds__(256) void gemm1_kernel(const ushort_t* __restrict__ hbfc,
                                                    const ushort_t* __restrict__ W1t,
                                                    const void* __restrict__ b1,
                                                    const int* __restrict__ modePtr,
                                                    const int* __restrict__ TcPtr,
                                                    ushort_t* __restrict__ hidc) {
    const int bm = blockIdx.x;
    if (bm * 64 >= *TcPtr) return;   // block-uniform early exit
    __shared__ ushort_t Al[64 * 64];    // 8 KB
    __shared__ ushort_t Bl[128 * 64];   // 16 KB
    const int f32m = modePtr[1];
    const int bn = blockIdx.y;
    const int tid = threadIdx.x;
    const int lane = tid & 63, w = tid >> 6;
    const int lm = lane & 15, quad = lane >> 4;
    const int wm = (w >> 1) * 32, wn = (w & 1) * 64;
    const ushort_t* Ab = hbfc + (size_t)(bm * 64) * D_;
    const ushort_t* Bb = W1t + (size_t)(bn * 128) * D_;
    f32x4 acc[2][4];
    const f32x4 zz = {0.f, 0.f, 0.f, 0.f};
#pragma unroll
    for (int i = 0; i < 2; ++i)
#pragma unroll
        for (int j = 0; j < 4; ++j) acc[i][j] = zz;
    const int r0 = tid >> 3, s0 = tid & 7;
    const int cg = ((s0 ^ (r0 & 7)) * 8);       // swizzled global col offset
    const int cl = s0 * 8;                      // LDS col (wave-contiguous)
    const int sa = ((lm & 7)) ;                 // read-side row swizzle key
    for (int kt = 0; kt < D_ / 64; ++kt) {
        const int kb = kt * 64;
        __syncthreads();
        ld16_lds(&Al[r0 * 64 + cl],        &Ab[(size_t)r0 * D_ + kb + cg]);
        ld16_lds(&Al[(r0 + 32) * 64 + cl], &Ab[(size_t)(r0 + 32) * D_ + kb + cg]);
        ld16_lds(&Bl[r0 * 64 + cl],        &Bb[(size_t)r0 * D_ + kb + cg]);
        ld16_lds(&Bl[(r0 + 32) * 64 + cl], &Bb[(size_t)(r0 + 32) * D_ + kb + cg]);
        ld16_lds(&Bl[(r0 + 64) * 64 + cl], &Bb[(size_t)(r0 + 64) * D_ + kb + cg]);
        ld16_lds(&Bl[(r0 + 96) * 64 + cl], &Bb[(size_t)(r0 + 96) * D_ + kb + cg]);
        __syncthreads();
#pragma unroll
        for (int kk = 0; kk < 2; ++kk) {
            const int oc = ((kk * 4 + quad) ^ sa) * 8;   // LDS slot of global octet kk*4+quad
            bf16x8 af[2], bfr[4];
#pragma unroll
            for (int i = 0; i < 2; ++i)
                af[i] = *(const bf16x8*)&Al[(wm + i * 16 + lm) * 64 + oc];
#pragma unroll
            for (int j = 0; j < 4; ++j)
                bfr[j] = *(const bf16x8*)&Bl[(wn + j * 16 + lm) * 64 + oc];
#pragma unroll
            for (int i = 0; i < 2; ++i)
#pragma unroll
                for (int j = 0; j < 4; ++j)
                    acc[i][j] = __builtin_amdgcn_mfma_f32_16x16x32_bf16(af[i], bfr[j], acc[i][j], 0, 0, 0);
        }
    }
#pragma unroll
    for (int j = 0; j < 4; ++j) {
        int n = bn * 128 + wn + j * 16 + lm;
        int kexp = n >> 9, fg = n & 511;
        float bias = loadF(b1, (size_t)n, f32m);
#pragma unroll
        for (int i = 0; i < 2; ++i) {
            int mb = bm * 64 + wm + i * 16 + quad * 4;
#pragma unroll
            for (int v = 0; v < 4; ++v) {
                float x = acc[i][j][v] + bias;
                float g = 0.5f * x * (1.0f + erff(x * 0.70710678118654752f));
                hidc[(size_t)kexp * T_ * F_ + (size_t)(mb + v) * F_ + fg] = f2bf(g);
            }
        }
    }
}

// ---------------- GEMM2 (z=expert; 64x128 tile, BK=64, swizzled, scatter) ----------------
__global__ __launch_bounds__(256) void gemm2_kernel(const ushort_t* __restrict__ hidc,
                                                    const ushort_t* __restrict__ W2t,
                                                    const void* __restrict__ b2,
                                                    const int* __restrict__ modePtr,
                                                    const int* __restrict__ TcPtr,
                                                    const int* __restrict__ idx,
                                                    ushort_t* __restrict__ eo) {
    const int bm = blockIdx.x;
    if (bm * 64 >= *TcPtr) return;
    __shared__ ushort_t Al[64 * 64];    // 8 KB
    __shared__ ushort_t Bl[128 * 64];   // 16 KB
    __shared__ int sidx[64];
    const int f32m = modePtr[1];
    const int kexp = blockIdx.z;
    const int bn = blockIdx.y;
    const int tid = threadIdx.x;
    if (tid < 64) sidx[tid] = idx[bm * 64 + tid];
    const int lane = tid & 63, w = tid >> 6;
    const int lm = lane & 15, quad = lane >> 4;
    const int wm = (w >> 1) * 32, wn = (w & 1) * 64;
    const ushort_t* Ab = hidc + (size_t)kexp * T_ * F_ + (size_t)(bm * 64) * F_;
    const ushort_t* Bb = W2t + (size_t)kexp * D_ * F_ + (size_t)(bn * 128) * F_;
    f32x4 acc[2][4];
    const f32x4 zz = {0.f, 0.f, 0.f, 0.f};
#pragma unroll
    for (int i = 0; i < 2; ++i)
#pragma unroll
        for (int j = 0; j < 4; ++j) acc[i][j] = zz;
    const int r0 = tid >> 3, s0 = tid & 7;
    const int cg = ((s0 ^ (r0 & 7)) * 8);
    const int cl = s0 * 8;
    const int sa = (lm & 7);
    for (int kt = 0; kt < F_ / 64; ++kt) {
        const int kb = kt * 64;
        __syncthreads();
        ld16_lds(&Al[r0 * 64 + cl],        &Ab[(size_t)r0 * F_ + kb + cg]);
        ld16_lds(&Al[(r0 + 32) * 64 + cl], &Ab[(size_t)(r0 + 32) * F_ + kb + cg]);
        ld16_lds(&Bl[r0 * 64 + cl],        &Bb[(size_t)r0 * F_ + kb + cg]);
        ld16_lds(&Bl[(r0 + 32) * 64 + cl], &Bb[(size_t)(r0 + 32) * F_ + kb + cg]);
        ld16_lds(&Bl[(r0 + 64) * 64 + cl], &Bb[(size_t)(r0 + 64) * F_ + kb + cg]);
        ld16_lds(&Bl[(r0 + 96) * 64 + cl], &Bb[(size_t)(r0 + 96) * F_ + kb + cg]);
        __syncthreads();
#pragma unroll
        for (int kk = 0; kk < 2; ++kk) {
            const int oc = ((kk * 4 + quad) ^ sa) * 8;
            bf16x8 af[2], bfr[4];
#pragma unroll
            for (int i = 0; i < 2; ++i)
                af[i] = *(const bf16x8*)&Al[(wm + i * 16 + lm) * 64 + oc];
#pragma unroll
            for (int j = 0; j < 4; ++j)
                bfr[j] = *(const bf16x8*)&Bl[(wn + j * 16 + lm) * 64 + oc];
#pragma unroll
            for (int i = 0; i < 2; ++i)
#pragma unroll
                for (int j = 0; j < 4; ++j)
                    acc[i][j] = __builtin_amdgcn_mfma_f32_16x16x32_bf16(af[i], bfr[j], acc[i][j], 0, 0, 0);
        }
    }
#pragma unroll
    for (int j = 0; j < 4; ++j) {
        int dg = bn * 128 + wn + j * 16 + lm;
        float bias = loadF(b2, (size_t)kexp * D_ + dg, f32m);
#pragma unroll
        for (int i = 0; i < 2; ++i) {
            int lr = wm + i * 16 + quad * 4;
#pragma unroll
            for (int v = 0; v < 4; ++v) {
                int tok = sidx[lr + v];   // sentinel T_ for padded rows
                float x = acc[i][j][v] + bias;
                eo[((size_t)tok * K_ + kexp) * D_ + dg] = f2bf(x);
            }
        }
    }
}

// ---------------- sliding window over all experts + routing mix (skips masked rows) ----------------
__device__ __forceinline__ void acc8add(float* run, const ushort_t* p) {
    const uint4 q = *(const uint4*)p;
    run[0] += __uint_as_float(q.x << 16);
    run[1] += __uint_as_float(q.x & 0xFFFF0000u);
    run[2] += __uint_as_float(q.y << 16);
    run[3] += __uint_as_float(q.y & 0xFFFF0000u);
    run[4] += __uint_as_float(q.z << 16);
    run[5] += __uint_as_float(q.z & 0xFFFF0000u);
    run[6] += __uint_as_float(q.w << 16);
    run[7] += __uint_as_float(q.w & 0xFFFF0000u);
}
__device__ __forceinline__ void acc8sub(float* run, const ushort_t* p) {
    const uint4 q = *(const uint4*)p;
    run[0] -= __uint_as_float(q.x << 16);
    run[1] -= __uint_as_float(q.x & 0xFFFF0000u);
    run[2] -= __uint_as_float(q.y << 16);
    run[3] -= __uint_as_float(q.y & 0xFFFF0000u);
    run[4] -= __uint_as_float(q.z << 16);
    run[5] -= __uint_as_float(q.z & 0xFFFF0000u);
    run[6] -= __uint_as_float(q.w << 16);
    run[7] -= __uint_as_float(q.w & 0xFFFF0000u);
}

__global__ __launch_bounds__(256) void window_all_kernel(const ushort_t* __restrict__ eo,
                                                         const float* __restrict__ wR,
                                                         const int* __restrict__ maskI,
                                                         const float* __restrict__ invcnt,
                                                         float* __restrict__ mixed) {
    const int b = blockIdx.y;
    const int s0 = blockIdx.x * WSEG;
    const int d0 = threadIdx.x * 8;
    float run[K_][8];
#pragma unroll
    for (int k = 0; k < K_; ++k)
#pragma unroll
        for (int j = 0; j < 8; ++j) run[k][j] = 0.f;
    int lo = s0 - R_; if (lo < 0) lo = 0;
    for (int sp = lo; sp < s0 + R_; ++sp) {
        if (maskI[b * S_ + sp]) continue;
        const ushort_t* row = &eo[(size_t)(b * S_ + sp) * K_ * D_ + d0];
#pragma unroll
        for (int k = 0; k < K_; ++k) acc8add(run[k], row + (size_t)k * D_);
    }
    for (int s = s0; s < s0 + WSEG; ++s) {
        const int t = b * S_ + s;
        if (s + R_ < S_ && !maskI[t + R_]) {
            const ushort_t* row = &eo[(size_t)(t + R_) * K_ * D_ + d0];
#pragma unroll
            for (int k = 0; k < K_; ++k) acc8add(run[k], row + (size_t)k * D_);
        }
        if (maskI[t]) {
            float ic = invcnt[t];
            float o[8];
#pragma unroll
            for (int j = 0; j < 8; ++j) o[j] = 0.f;
#pragma unroll
            for (int k = 0; k < K_; ++k) {
                float wk = wR[t * K_ + k] * ic;
#pragma unroll
                for (int j = 0; j < 8; ++j) o[j] += wk * run[k][j];
            }
            float4 o0 = {o[0], o[1], o[2], o[3]};
            float4 o1 = {o[4], o[5], o[6], o[7]};
            *(float4*)&mixed[(size_t)t * D_ + d0]     = o0;
            *(float4*)&mixed[(size_t)t * D_ + d0 + 4] = o1;
        }
        if (s - R_ >= 0 && !maskI[t - R_]) {
            const ushort_t* row = &eo[(size_t)(t - R_) * K_ * D_ + d0];
#pragma unroll
            for (int k = 0; k < K_; ++k) acc8sub(run[k], row + (size_t)k * D_);
        }
    }
}

// ---------------- LayerNorm + validity mask; dtype-aware output ----------------
__global__ __launch_bounds__(256) void ln_kernel(const float* __restrict__ mixed,
                                                 const int* __restrict__ valid,
                                                 const int* __restrict__ modePtr,
                                                 void* __restrict__ out) {
    const int t = blockIdx.x;
    const int tid = threadIdx.x;
    const int f32m = modePtr[1];
    if (!valid[t]) {
        if (f32m) {
            float4 z = {0.f, 0.f, 0.f, 0.f};
            float* op = (float*)out + (size_t)t * D_ + tid * 8;
            *(float4*)op = z; *(float4*)(op + 4) = z;
        } else {
            uint4 z = {0u, 0u, 0u, 0u};
            *(uint4*)((ushort_t*)out + (size_t)t * D_ + tid * 8) = z;
        }
        return;
    }
    float4 a = *(const float4*)&mixed[(size_t)t * D_ + tid * 8];
    float4 c = *(const float4*)&mixed[(size_t)t * D_ + tid * 8 + 4];
    float xs[8] = {a.x, a.y, a.z, a.w, c.x, c.y, c.z, c.w};
    float s1 = 0.f, s2 = 0.f;
#pragma unroll
    for (int j = 0; j < 8; ++j) { s1 += xs[j]; s2 += xs[j] * xs[j]; }
#pragma unroll
    for (int off = 32; off; off >>= 1) { s1 += __shfl_down(s1, off); s2 += __shfl_down(s2, off); }
    __shared__ float sm[8];
    int w = tid >> 6;
    if ((tid & 63) == 0) { sm[w * 2] = s1; sm[w * 2 + 1] = s2; }
    __syncthreads();
    float ts1 = sm[0] + sm[2] + sm[4] + sm[6];
    float ts2 = sm[1] + sm[3] + sm[5] + sm[7];
    float mu = ts1 * (1.0f / D_);
    float var = fmaxf(ts2 * (1.0f / D_) - mu * mu, 0.0f);
    float inv = rsqrtf(var + 1e-5f);
    if (f32m) {
        float* op = (float*)out + (size_t)t * D_ + tid * 8;
        float4 o0 = {(xs[0] - mu) * inv, (xs[1] - mu) * inv, (xs[2] - mu) * inv, (xs[3] - mu) * inv};
        float4 o1 = {(xs[4] - mu) * inv, (xs[5] - mu) * inv, (xs[6] - mu) * inv, (xs[7] - mu) * inv};
        *(float4*)op = o0; *(float4*)(op + 4) = o1;
    } else {
        ushort_t ob[8];
#pragma unroll
        for (int j = 0; j < 8; ++j) ob[j] = f2bf((xs[j] - mu) * inv);
        uint4 o;
        o.x = (unsigned)ob[0] | ((unsigned)ob[1] << 16);
        o.y = (unsigned)ob[2] | ((unsigned)ob[3] << 16);
        o.z = (unsigned)ob[4] | ((unsigned)ob[5] << 16);
        o.w = (unsigned)ob[6] | ((unsigned)ob[7] << 16);
        *(uint4*)((ushort_t*)out + (size_t)t * D_ + tid * 8) = o;
    }
}

extern "C" void kernel_launch(void* const* d_in, const int* in_sizes, int n_in,
                              void* d_out, int out_size, void* d_ws, size_t ws_size,
                              hipStream_t stream) {
    const void* h    = d_in[0];
    const void* mraw = d_in[1];
    const void* Wr   = d_in[2];
    const void* br   = d_in[3];
    const void* W1   = d_in[4];
    const void* b1   = d_in[5];
    const void* W2   = d_in[6];
    const void* b2   = d_in[7];
    (void)in_sizes; (void)n_in; (void)out_size; (void)ws_size;

    char* ws = (char*)d_ws;
    size_t off = 0;
    auto alloc = [&](size_t bytes) -> void* {
        void* p = ws + off;
        off += (bytes + 255) & ~(size_t)255;
        return p;
    };
    ushort_t* hbfc  = (ushort_t*)alloc((size_t)T_ * D_ * 2);              // 16.8 MB
    ushort_t* W1t   = (ushort_t*)alloc((size_t)K_ * F_ * D_ * 2);         // 16.8 MB [K][F][D] == B^T[4096][2048]
    ushort_t* W2t   = (ushort_t*)alloc((size_t)K_ * D_ * F_ * 2);         // 16.8 MB [K][D][F]
    ushort_t* hidc  = (ushort_t*)alloc((size_t)K_ * T_ * F_ * 2);         // 33.6 MB [K][Tc][F]
    ushort_t* eo    = (ushort_t*)alloc(((size_t)T_ + 1) * K_ * D_ * 2);   // 134 MB + sentinel row
    float*    wRbuf = (float*)alloc((size_t)T_ * K_ * 4);
    int*      maskI = (int*)alloc((size_t)T_ * 4);
    float*    invc  = (float*)alloc((size_t)T_ * 4);
    int*      valid = (int*)alloc((size_t)T_ * 4);
    int*      idx   = (int*)alloc((size_t)T_ * 4);
    int*      Tc    = (int*)alloc(256);
    int*      mode  = (int*)alloc(256);
    float*    mixed = (float*)hidc;   // aliases hidc (dead after gemm2)

    hipLaunchKernelGGL(detect_kernel, dim3(1), dim3(256), 0, stream,
                       (const unsigned char*)h, (const unsigned char*)mraw, mode);
    hipLaunchKernelGGL(mask_prep_kernel, dim3(1), dim3(256), 0, stream,
                       mraw, mode, maskI, idx, Tc, invc, valid);
    hipLaunchKernelGGL(conv_hc_kernel, dim3(T_ * D_ / 8 / 256), dim3(256), 0, stream,
                       h, mode, idx, Tc, hbfc);
    hipLaunchKernelGGL(router_kernel, dim3(T_), dim3(256), 0, stream,
                       h, Wr, br, mode, maskI, wRbuf);
    hipLaunchKernelGGL(transpose_kernel, dim3(D_ / 32, F_ / 32, K_), dim3(256), 0, stream,
                       W1, W1t, D_, F_, mode);
    hipLaunchKernelGGL(transpose_kernel, dim3(F_ / 32, D_ / 32, K_), dim3(256), 0, stream,
                       W2, W2t, F_, D_, mode);
    hipLaunchKernelGGL(gemm1_kernel, dim3(T_ / 64, K_ * F_ / 128), dim3(256), 0, stream,
                       hbfc, W1t, b1, mode, Tc, hidc);
    hipLaunchKernelGGL(gemm2_kernel, dim3(T_ / 64, D_ / 128, K_), dim3(256), 0, stream,
                       hidc, W2t, b2, mode, Tc, idx, eo);
    hipLaunchKernelGGL(window_all_kernel, dim3(S_ / WSEG, B_), dim3(256), 0, stream,
                       eo, wRbuf, maskI, invc, mixed);
    hipLaunchKernelGGL(ln_kernel, dim3(T_), dim3(256), 0, stream,
                       mixed, valid, mode, d_out);
}